// Round 2
// baseline (377.502 us; speedup 1.0000x reference)
//
#include <hip/hip_runtime.h>

// ContinuousWaveletTransform on MI355X.
// x: (8,16,128,1024) fp32 -> out: (8,16,4,128,1024) fp32.
// out[b,c,s,h,w] = sum_{dt=-64..64} x_zeroext[b,c,h,w+dt] * bank[s, dt+64]
// (XLA conv = correlation, no flip; bank is even-symmetric; H-pad is cropped
//  away untouched; W-pad+SAME+crop == zero-extended correlation.)

namespace {

// ---------- constexpr double-precision math for the wavelet bank ----------
constexpr double kLn2Hi  = 6.93147180369123816490e-01;
constexpr double kLn2Lo  = 1.90821492927058770002e-10;
constexpr double kInvLn2 = 1.4426950408889634074;

constexpr double cexp(double x) {          // accurate for x in [-60, 0]
  int k = (int)(x * kInvLn2 + (x >= 0 ? 0.5 : -0.5));
  double r = (x - k * kLn2Hi) - k * kLn2Lo;
  double term = 1.0, sum = 1.0;
  for (int n = 1; n <= 17; ++n) { term *= r / n; sum += term; }
  double p = 1.0;
  int a = k < 0 ? -k : k;
  for (int i = 0; i < a; ++i) p *= 2.0;
  return k < 0 ? sum / p : sum * p;
}

constexpr double kPio2Hi = 1.57079632679489655800e+00;
constexpr double kPio2Lo = 6.12323399573676603587e-17;

constexpr double csin_poly(double r) {
  double r2 = r * r, term = r, sum = r;
  for (int n = 1; n <= 10; ++n) { term *= -r2 / ((2.0*n) * (2.0*n + 1.0)); sum += term; }
  return sum;
}
constexpr double ccos_poly(double r) {
  double r2 = r * r, term = 1.0, sum = 1.0;
  for (int n = 1; n <= 10; ++n) { term *= -r2 / ((2.0*n - 1.0) * (2.0*n)); sum += term; }
  return sum;
}
constexpr double ccos(double x) {          // x >= 0, x <= ~40
  double ax = x < 0 ? -x : x;
  int n = (int)(ax / 1.5707963267948966 + 0.5);
  double r = (ax - n * kPio2Hi) - n * kPio2Lo;
  switch (n & 3) {
    case 0: return  ccos_poly(r);
    case 1: return -csin_poly(r);
    case 2: return -ccos_poly(r);
    default: return  csin_poly(r);
  }
}

struct Bank { float c[4][65]; };
constexpr Bank make_bank() {
  Bank b{};
  const double scales[4]  = {2.0, 4.0, 8.0, 16.0};
  const double rsqrt_s[4] = {0.70710678118654752440, 0.5,
                             0.35355339059327376220, 0.25};
  for (int s = 0; s < 4; ++s)
    for (int t = 0; t <= 64; ++t) {
      double u = (double)t / scales[s];
      b.c[s][t] = (float)(cexp(-0.5 * u * u) * ccos(5.0 * u) * rsqrt_s[s]);
    }
  return b;
}
__device__ constexpr Bank kBank = make_bank();
// Truncation radii: coeff < ~1e-10 beyond 6.8*s -> exact at fp32 level.
constexpr int kR[4] = {14, 28, 55, 64};

// ---------- kernel ----------
constexpr int kW    = 1024;
constexpr int kH    = 128;
constexpr int kHalf = 64;
constexpr int kT    = 4;                 // pixels per thread
constexpr int kWin  = kT + 2 * kHalf;    // 132-float register window
constexpr int kLdsN = kW + 2 * kHalf;    // 1152 floats (4.6 KB)

__global__ __launch_bounds__(256)
void cwt_kernel(const float* __restrict__ x, float* __restrict__ out) {
  const int row = blockIdx.x;            // (b*C + c)*H + h, 16384 rows
  const int tid = threadIdx.x;
  const float* __restrict__ xr = x + (size_t)row * kW;

  __shared__ float lds[kLdsN];
  // Stage row + zero halo, float4-coalesced. 288 float4s over 256 threads.
  for (int k = tid; k < kLdsN / 4; k += 256) {
    const int j0 = 4 * k - kHalf;        // element index into the row
    float4 v = make_float4(0.f, 0.f, 0.f, 0.f);
    if (j0 >= 0 && j0 + 4 <= kW)
      v = *reinterpret_cast<const float4*>(xr + j0);
    *reinterpret_cast<float4*>(&lds[4 * k]) = v;
  }
  __syncthreads();

  // Register window: w[j] = x_zeroext[p0 + j - 64]; pixel p0+i sits at w[64+i].
  const int p0 = tid * kT;
  float w[kWin];
#pragma unroll
  for (int j = 0; j < kWin / 4; ++j)
    *reinterpret_cast<float4*>(&w[4 * j]) =
        *reinterpret_cast<const float4*>(&lds[p0 + 4 * j]);

  float acc[4][kT];
#pragma unroll
  for (int s = 0; s < 4; ++s)
#pragma unroll
    for (int i = 0; i < kT; ++i)
      acc[s][i] = kBank.c[s][0] * w[kHalf + i];

#pragma unroll
  for (int dt = 1; dt <= kHalf; ++dt) {
    float p[kT];
#pragma unroll
    for (int i = 0; i < kT; ++i)
      p[i] = w[kHalf + i - dt] + w[kHalf + i + dt];   // shared pairsum
#pragma unroll
    for (int s = 0; s < 4; ++s) {
      if (dt <= kR[s]) {                 // compile-time pruned after unroll
#pragma unroll
        for (int i = 0; i < kT; ++i)
          acc[s][i] += kBank.c[s][dt] * p[i];
      }
    }
  }

  // out layout (B,C,S,H,W): offset = ((bc*4 + s)*H + h)*W + p0
  const int bc = row >> 7;               // / kH
  const int h  = row & (kH - 1);
  float* op = out + ((size_t)bc * 4) * (size_t)(kH * kW)
                  + (size_t)h * kW + p0;
#pragma unroll
  for (int s = 0; s < 4; ++s) {
    float4 v = make_float4(acc[s][0], acc[s][1], acc[s][2], acc[s][3]);
    *reinterpret_cast<float4*>(op + (size_t)s * (kH * kW)) = v;
  }
}

}  // namespace

extern "C" void kernel_launch(void* const* d_in, const int* in_sizes, int n_in,
                              void* d_out, int out_size, void* d_ws, size_t ws_size,
                              hipStream_t stream) {
  const float* x = (const float*)d_in[0];
  float* out = (float*)d_out;
  const int rows = 8 * 16 * 128;         // 16384 blocks, one row each
  cwt_kernel<<<dim3(rows), dim3(256), 0, stream>>>(x, out);
}